// Round 1
// baseline (364.373 us; speedup 1.0000x reference)
//
#include <hip/hip_runtime.h>
#include <math.h>

// PointcloudToVoxels: B=4 batches, C=32 channels, N=200k points,
// 64x64x64 grid, V = 262144 voxels.
// Output layout: [B,C,V] voxeldata (float32) then [B,1,V] occupancy (float32).
//
// R4 finding: device-scope atomics execute memory-side (~26 G atomics/s),
// so counting sort (1 atomic per point) beats per-(point,channel) atomicMax.
// R5 theory: v1's segmax (thread per (b,c,v), random 4B gathers via
// sorted_idx) moves 1.6-3.2 GB of L2 lines for 102 MB of useful data and is
// latency-chained + divergence-starved (~17% active lanes). Fix: materialize
// the sort. sortscatter moves each point's 32 channels once (coalesced
// stride-N reads, one contiguous 128B write at its sorted position); segmaxT
// then runs ONE thread per (b,v) reading dense sequential 128B chunks with
// 32 register accumulators and 32 wave-coalesced stores to [B,C,V].

#define GW 64
#define GL 64
#define GH 64
#define GV (GW * GL * GH)   // 262144 = 2^18
#define NB 4
#define MIN_PTS 10

// Binning that bit-matches XLA's compilation of floor(x/0.05 + 0.5):
// XLA folds x/0.05 -> x * 20.0f (fl32(1/0.05) == 20.0f exactly);
// __fmul_rn/__fadd_rn forbid FMA contraction. [R3: absmax 0.0 with this.]
__device__ __forceinline__ int bin_coord(float x) {
    float m = __fmul_rn(x, 20.0f);
    float r = __fadd_rn(m, 0.5f);
    return (int)floorf(r);
}

__global__ void zero_kernel(uint4* __restrict__ p, int n4) {
    int i = blockIdx.x * blockDim.x + threadIdx.x;
    if (i < n4) p[i] = make_uint4(0u, 0u, 0u, 0u);
}

// Phase 1: per-point voxel id + rank within voxel (one returning atomic per
// in-bounds point). Rank order is nondeterministic but max is commutative.
__global__ void hist_kernel(const float* __restrict__ coords,
                            int* __restrict__ counts,
                            int* __restrict__ vox,
                            int* __restrict__ rank,
                            int N) {
    int n = blockIdx.x * blockDim.x + threadIdx.x;
    int b = blockIdx.y;
    if (n >= N) return;
    const float* pc = coords + (size_t)b * 3 * N;
    int ix = bin_coord(pc[n]);
    int iy = bin_coord(pc[n + N]);
    int iz = bin_coord(pc[n + 2 * N]);
    bool ok = (unsigned)ix < (unsigned)GW && (unsigned)iy < (unsigned)GL &&
              (unsigned)iz < (unsigned)GH;
    int v = ok ? ((ix << 12) | (iy << 6) | iz) : -1;
    vox[(size_t)b * N + n] = v;
    if (ok) rank[(size_t)b * N + n] = atomicAdd(&counts[b * GV + v], 1);
}

// Phase 2a: per-block (1024 elements) exclusive scan + block sums.
__global__ void scan_blocks_kernel(const int* __restrict__ counts,
                                   int* __restrict__ offsets,
                                   int* __restrict__ blocksums) {
    __shared__ int lds[256];
    int t = threadIdx.x;
    int base = blockIdx.x * 1024 + t * 4;
    int4 c = *(const int4*)&counts[base];
    int s0 = c.x, s1 = s0 + c.y, s2 = s1 + c.z, s3 = s2 + c.w;
    lds[t] = s3;
    __syncthreads();
    for (int d = 1; d < 256; d <<= 1) {
        int v = (t >= d) ? lds[t - d] : 0;
        __syncthreads();
        if (t >= d) lds[t] += v;
        __syncthreads();
    }
    int excl = (t > 0) ? lds[t - 1] : 0;
    int4 o;
    o.x = excl; o.y = excl + s0; o.z = excl + s1; o.w = excl + s2;
    *(int4*)&offsets[base] = o;
    if (t == 255) blocksums[blockIdx.x] = lds[255];
}

// Phase 2b: exclusive scan of the 1024 block sums (single block), in place.
__global__ void scan_sums_kernel(int* __restrict__ blocksums) {
    __shared__ int lds[256];
    int t = threadIdx.x;
    int4 c = *(const int4*)&blocksums[t * 4];
    int s0 = c.x, s1 = s0 + c.y, s2 = s1 + c.z, s3 = s2 + c.w;
    lds[t] = s3;
    __syncthreads();
    for (int d = 1; d < 256; d <<= 1) {
        int v = (t >= d) ? lds[t - d] : 0;
        __syncthreads();
        if (t >= d) lds[t] += v;
        __syncthreads();
    }
    int excl = (t > 0) ? lds[t - 1] : 0;
    int4 o;
    o.x = excl; o.y = excl + s0; o.z = excl + s1; o.w = excl + s2;
    *(int4*)&blocksums[t * 4] = o;
}

// Phase 2c: add block offsets.
__global__ void scan_add_kernel(int* __restrict__ offsets,
                                const int* __restrict__ blocksums) {
    int i = blockIdx.x * blockDim.x + threadIdx.x;   // uint4 index
    int s = blocksums[(i * 4) >> 10];
    int4 o = *(int4*)&offsets[i * 4];
    o.x += s; o.y += s; o.z += s; o.w += s;
    *(int4*)&offsets[i * 4] = o;
}

// ---------------------------------------------------------------------------
// R5 fast path: materialized sort of channel vectors.
//
// Phase 3': for each in-bounds point, read its 32 channels (32 wave-coalesced
// stride-N loads -> register transpose) and write ONE contiguous 128B chunk
// at sortedT[pos*32]. Scattered across lanes but every 64B line fully written
// (pos*128 is 128B-aligned) -> no RMW read traffic, no partial lines.
__global__ void sortscatter_kernel(const float* __restrict__ attrs,
                                   const int* __restrict__ vox,
                                   const int* __restrict__ rank,
                                   const int* __restrict__ offsets,
                                   float* __restrict__ sortedT,
                                   size_t sortedStride,   // floats per batch slot
                                   int b0, int N) {
    int n = blockIdx.x * blockDim.x + threadIdx.x;
    int b = b0 + blockIdx.y;
    if (n >= N) return;
    int v = vox[(size_t)b * N + n];
    if (v < 0) return;
    int base = offsets[b * GV];                       // batch region start (L2 bcast)
    int pos = offsets[b * GV + v] + rank[(size_t)b * N + n] - base;
    const float* pa = attrs + (size_t)b * 32 * N + n;
    float* dst = sortedT + (size_t)blockIdx.y * sortedStride + (size_t)pos * 32;
#pragma unroll
    for (int c = 0; c < 32; c += 4) {
        float4 w;
        w.x = pa[(size_t)(c + 0) * N];
        w.y = pa[(size_t)(c + 1) * N];
        w.z = pa[(size_t)(c + 2) * N];
        w.w = pa[(size_t)(c + 3) * N];
        *(float4*)&dst[c] = w;
    }
}

// Phase 4': one thread per (b,v). Segment data is dense and sequential in
// sortedT; adjacent lanes (adjacent v) read adjacent regions -> every fetched
// line fully consumed. 32 running maxes live in registers (all indices
// compile-time constant -> no scratch). 32 stores, each wave-coalesced over v
// into the required [B,C,V] layout.
__global__ void segmaxT_kernel(const float* __restrict__ sortedT,
                               const int* __restrict__ counts,
                               const int* __restrict__ offsets,
                               float* __restrict__ vdata,
                               float* __restrict__ occ,
                               size_t sortedStride,   // floats per batch slot
                               int b0) {
    int v = blockIdx.x * blockDim.x + threadIdx.x;    // grid covers GV exactly
    int b = b0 + blockIdx.y;
    int bv = b * GV + v;
    int cnt = counts[bv];
    int off = offsets[bv] - offsets[b * GV];
    const float* src = sortedT + (size_t)blockIdx.y * sortedStride
                               + (size_t)off * 32;
    float4 m[8];
#pragma unroll
    for (int j = 0; j < 8; ++j)
        m[j] = make_float4(-INFINITY, -INFINITY, -INFINITY, -INFINITY);
    for (int k = 0; k < cnt; ++k) {
        const float4* p = (const float4*)(src + (size_t)k * 32);
#pragma unroll
        for (int j = 0; j < 8; ++j) {
            float4 x = p[j];
            m[j].x = fmaxf(m[j].x, x.x);
            m[j].y = fmaxf(m[j].y, x.y);
            m[j].z = fmaxf(m[j].z, x.z);
            m[j].w = fmaxf(m[j].w, x.w);
        }
    }
    float* out = vdata + (((size_t)b * 32) << 18) + v;
    bool nz = cnt > 0;
#pragma unroll
    for (int j = 0; j < 8; ++j) {
        out[((size_t)(4 * j + 0)) << 18] = nz ? m[j].x : 0.0f;
        out[((size_t)(4 * j + 1)) << 18] = nz ? m[j].y : 0.0f;
        out[((size_t)(4 * j + 2)) << 18] = nz ? m[j].z : 0.0f;
        out[((size_t)(4 * j + 3)) << 18] = nz ? m[j].w : 0.0f;
    }
    occ[bv] = (cnt >= MIN_PTS) ? 1.0f : 0.0f;
}

// ---------------------------------------------------------------------------
// v1 path (R4, 451us): kept as middle tier when ws is too small for sortedT.

// Phase 3: scatter point index into voxel-sorted position.
__global__ void scatter_idx_kernel(const int* __restrict__ vox,
                                   const int* __restrict__ rank,
                                   const int* __restrict__ offsets,
                                   int* __restrict__ sorted_idx,
                                   int N) {
    int n = blockIdx.x * blockDim.x + threadIdx.x;
    int b = blockIdx.y;
    if (n >= N) return;
    int v = vox[(size_t)b * N + n];
    if (v < 0) return;
    sorted_idx[offsets[b * GV + v] + rank[(size_t)b * N + n]] = n;
}

// Phase 4: segmented max, thread = (b, c, v).
__global__ void segmax_kernel(const float* __restrict__ attrs,
                              const int* __restrict__ counts,
                              const int* __restrict__ offsets,
                              const int* __restrict__ sorted_idx,
                              float* __restrict__ vdata,
                              float* __restrict__ occ,
                              int N) {
    int t = blockIdx.x * blockDim.x + threadIdx.x;   // < NB*32*GV = 2^25
    int v = t & (GV - 1);
    int c = (t >> 18) & 31;
    int b = t >> 23;
    int bv = (b << 18) | v;
    int cnt = counts[bv];
    int off = offsets[bv];
    const float* row = attrs + ((size_t)(b * 32 + c)) * N;
    float m = -INFINITY;
    for (int k = 0; k < cnt; ++k) {
        m = fmaxf(m, row[sorted_idx[off + k]]);
    }
    vdata[((size_t)(b * 32 + c) << 18) | v] = (cnt > 0) ? m : 0.0f;
    if (c == 0) occ[bv] = (cnt >= MIN_PTS) ? 1.0f : 0.0f;
}

// ---------------------------------------------------------------------------
// FALLBACK PATH (R3): direct atomicMax into d_out, any C. (absmax 0, 1206us)
__device__ __forceinline__ unsigned enc_f32(float f) {
    unsigned u = __float_as_uint(f);
    return (u & 0x80000000u) ? ~u : (u | 0x80000000u);
}
__device__ __forceinline__ float dec_f32(unsigned u) {
    return (u & 0x80000000u) ? __uint_as_float(u & 0x7FFFFFFFu)
                             : __uint_as_float(~u);
}

__global__ void init_kernel(uint4* __restrict__ data4, uint4* __restrict__ cnt4,
                            int nData4, int nCnt4) {
    int i = blockIdx.x * blockDim.x + threadIdx.x;
    uint4 z = make_uint4(0u, 0u, 0u, 0u);
    if (i < nData4) data4[i] = z;
    else if (i < nData4 + nCnt4) cnt4[i - nData4] = z;
}

__global__ void scatter_kernel(const float* __restrict__ coords,
                               const float* __restrict__ attrs,
                               unsigned* __restrict__ bits,
                               int* __restrict__ counts,
                               int N, int C) {
    int n = blockIdx.x * blockDim.x + threadIdx.x;
    int b = blockIdx.y;
    if (n >= N) return;
    const float* pc = coords + (size_t)b * 3 * N;
    int ix = bin_coord(pc[n]);
    int iy = bin_coord(pc[n + N]);
    int iz = bin_coord(pc[n + 2 * N]);
    if ((unsigned)ix >= (unsigned)GW || (unsigned)iy >= (unsigned)GL ||
        (unsigned)iz >= (unsigned)GH)
        return;
    int v = (ix << 12) | (iy << 6) | iz;
    atomicAdd(&counts[b * GV + v], 1);
    const float* pa = attrs + (size_t)b * C * N + n;
    unsigned* pb = bits + (size_t)b * C * GV + v;
    for (int c = 0; c < C; ++c)
        atomicMax(&pb[(size_t)c * GV], enc_f32(pa[(size_t)c * N]));
}

__global__ void finalize_kernel(unsigned* __restrict__ data,
                                const int* __restrict__ counts,
                                float* __restrict__ occ, int C) {
    int i = blockIdx.x * blockDim.x + threadIdx.x;
    int nData4 = NB * C * GV / 4;
    int nOcc4 = NB * GV / 4;
    if (i < nData4) {
        int idx = i << 2;
        int v = idx & (GV - 1);
        int b = idx / (C * GV);
        int4 cv = *(const int4*)&counts[b * GV + v];
        uint4 u = *(const uint4*)&data[idx];
        float4 r;
        r.x = cv.x > 0 ? dec_f32(u.x) : 0.0f;
        r.y = cv.y > 0 ? dec_f32(u.y) : 0.0f;
        r.z = cv.z > 0 ? dec_f32(u.z) : 0.0f;
        r.w = cv.w > 0 ? dec_f32(u.w) : 0.0f;
        *(float4*)&data[idx] = r;
    } else if (i < nData4 + nOcc4) {
        int j = (i - nData4) << 2;
        int4 cv = *(const int4*)&counts[j];
        float4 r;
        r.x = cv.x >= MIN_PTS ? 1.0f : 0.0f;
        r.y = cv.y >= MIN_PTS ? 1.0f : 0.0f;
        r.z = cv.z >= MIN_PTS ? 1.0f : 0.0f;
        r.w = cv.w >= MIN_PTS ? 1.0f : 0.0f;
        *(float4*)&occ[j] = r;
    }
}

// ---------------------------------------------------------------------------
extern "C" void kernel_launch(void* const* d_in, const int* in_sizes, int n_in,
                              void* d_out, int out_size, void* d_ws, size_t ws_size,
                              hipStream_t stream) {
    const float* coords = (const float*)d_in[0];  // [B,3,N]
    const float* attrs  = (const float*)d_in[1];  // [B,C,N]
    int N = in_sizes[0] / (NB * 3);
    int C = in_sizes[1] / (NB * N);

    // Common ws prefix: counts[B*GV] | offsets[B*GV] | blocksums[4096]
    //                   | vox[B*N] | rank[B*N]
    size_t wsCommon = (size_t)(2 * NB * GV + 4096 + 2 * NB * N) * 4;  // ~14.8MB
    size_t oneT  = (size_t)N * 32 * 4;        // 25.6MB, sortedT for one batch
    size_t fullT = (size_t)NB * N * 32 * 4;   // 102.4MB, sortedT for all
    size_t wsV1  = wsCommon + (size_t)NB * N * 4;  // + sorted_idx (~18MB)

    if (C == 32 && ws_size >= wsCommon + oneT) {
        // ------------------- R5 path: materialized channel-vector sort ------
        int* counts    = (int*)d_ws;
        int* offsets   = counts + (size_t)NB * GV;
        int* blocksums = offsets + (size_t)NB * GV;
        int* vox       = blocksums + 4096;
        int* rank      = vox + (size_t)NB * N;
        float* sortedT = (float*)(rank + (size_t)NB * N);
        float* vdata   = (float*)d_out;                       // [B,32,V]
        float* occ     = (float*)d_out + (size_t)NB * 32 * GV;

        int nCnt4 = NB * GV / 4;                              // 262144
        zero_kernel<<<(nCnt4 + 255) / 256, 256, 0, stream>>>((uint4*)counts,
                                                             nCnt4);
        dim3 pgrid((N + 255) / 256, NB);
        hist_kernel<<<pgrid, 256, 0, stream>>>(coords, counts, vox, rank, N);

        scan_blocks_kernel<<<NB * GV / 1024, 256, 0, stream>>>(counts, offsets,
                                                               blocksums);
        scan_sums_kernel<<<1, 256, 0, stream>>>(blocksums);
        scan_add_kernel<<<NB * GV / 1024, 256, 0, stream>>>(offsets, blocksums);

        if (ws_size >= wsCommon + fullT) {
            // All batches in one pass (fewer launches, no tails).
            sortscatter_kernel<<<dim3((N + 255) / 256, NB), 256, 0, stream>>>(
                attrs, vox, rank, offsets, sortedT, (size_t)N * 32, 0, N);
            segmaxT_kernel<<<dim3(GV / 256, NB), 256, 0, stream>>>(
                sortedT, counts, offsets, vdata, occ, (size_t)N * 32, 0);
        } else {
            // One batch at a time, sortedT reused (25.6MB scratch).
            for (int b = 0; b < NB; ++b) {
                sortscatter_kernel<<<dim3((N + 255) / 256, 1), 256, 0, stream>>>(
                    attrs, vox, rank, offsets, sortedT, 0, b, N);
                segmaxT_kernel<<<dim3(GV / 256, 1), 256, 0, stream>>>(
                    sortedT, counts, offsets, vdata, occ, 0, b);
            }
        }
    } else if (C == 32 && ws_size >= wsV1) {
        // ------------------- R4 path: index sort + per-channel gather -------
        int* counts     = (int*)d_ws;
        int* offsets    = counts + (size_t)NB * GV;
        int* blocksums  = offsets + (size_t)NB * GV;
        int* vox        = blocksums + 4096;
        int* rank       = vox + (size_t)NB * N;
        int* sorted_idx = rank + (size_t)NB * N;
        float* vdata    = (float*)d_out;                      // [B,32,V]
        float* occ      = (float*)d_out + (size_t)NB * 32 * GV;

        int nCnt4 = NB * GV / 4;
        zero_kernel<<<(nCnt4 + 255) / 256, 256, 0, stream>>>((uint4*)counts,
                                                             nCnt4);
        dim3 pgrid((N + 255) / 256, NB);
        hist_kernel<<<pgrid, 256, 0, stream>>>(coords, counts, vox, rank, N);

        scan_blocks_kernel<<<NB * GV / 1024, 256, 0, stream>>>(counts, offsets,
                                                               blocksums);
        scan_sums_kernel<<<1, 256, 0, stream>>>(blocksums);
        scan_add_kernel<<<NB * GV / 1024, 256, 0, stream>>>(offsets, blocksums);

        scatter_idx_kernel<<<pgrid, 256, 0, stream>>>(vox, rank, offsets,
                                                      sorted_idx, N);

        int segThreads = NB * 32 * GV;                        // 2^25
        segmax_kernel<<<segThreads / 256, 256, 0, stream>>>(
            attrs, counts, offsets, sorted_idx, vdata, occ, N);
    } else {
        unsigned* bits = (unsigned*)d_out;
        float* occ = (float*)d_out + (size_t)NB * C * GV;
        int* counts = (int*)d_ws;
        int nData4 = NB * C * GV / 4;
        int nCnt4 = NB * GV / 4;
        int initTotal = nData4 + nCnt4;
        init_kernel<<<(initTotal + 255) / 256, 256, 0, stream>>>(
            (uint4*)d_out, (uint4*)d_ws, nData4, nCnt4);
        dim3 sgrid((N + 255) / 256, NB);
        scatter_kernel<<<sgrid, 256, 0, stream>>>(coords, attrs, bits, counts,
                                                  N, C);
        finalize_kernel<<<(initTotal + 255) / 256, 256, 0, stream>>>(
            bits, counts, occ, C);
    }
}

// Round 2
// 335.743 us; speedup vs baseline: 1.0853x; 1.0853x over previous
//
#include <hip/hip_runtime.h>
#include <math.h>

// PointcloudToVoxels: B=4, C=32, N=200k, 64^3 grid, V=262144.
// Output: [B,C,V] voxeldata (f32) then [B,1,V] occupancy (f32).
//
// R4: device-scope atomics are memory-side (~26 G/s) -> counting sort.
// R5: materialized channel-vector sort (sortscatter + segmaxT), 364us.
//     Counters: sortscatter WRITE_SIZE 237.6MB vs 102.4MB useful (2.3x
//     amplification), VALUBusy 0.74%, 33% HBM peak. Cause: per-instruction
//     the wave's 64 lanes write 16B to 64 scattered lines -> partial-line
//     transactions, never merged.
// R6: (a) sortscatter2: LDS transpose so each destination 128B chunk is
//     written by ONE instruction (8 lanes x consecutive float4) -> full-line
//     merges at the coalescer. (b) segmax2: lane=(voxel-pair,channel), all
//     64 lanes active per 128B segment read, divergence = max of 2 cnts
//     instead of 64; output transposed through LDS for coalesced stores.

#define GW 64
#define GL 64
#define GH 64
#define GV (GW * GL * GH)   // 262144 = 2^18
#define NB 4
#define MIN_PTS 10

// Binning that bit-matches XLA's floor(x/0.05 + 0.5) (x/0.05 folds to
// x*20.0f exactly; __fmul_rn/__fadd_rn forbid FMA contraction). [R3: absmax 0]
__device__ __forceinline__ int bin_coord(float x) {
    float m = __fmul_rn(x, 20.0f);
    float r = __fadd_rn(m, 0.5f);
    return (int)floorf(r);
}

__global__ void zero_kernel(uint4* __restrict__ p, int n4) {
    int i = blockIdx.x * blockDim.x + threadIdx.x;
    if (i < n4) p[i] = make_uint4(0u, 0u, 0u, 0u);
}

// Phase 1: per-point voxel id + rank (one returning atomic per in-bounds pt).
__global__ void hist_kernel(const float* __restrict__ coords,
                            int* __restrict__ counts,
                            int* __restrict__ vox,
                            int* __restrict__ rank,
                            int N) {
    int n = blockIdx.x * blockDim.x + threadIdx.x;
    int b = blockIdx.y;
    if (n >= N) return;
    const float* pc = coords + (size_t)b * 3 * N;
    int ix = bin_coord(pc[n]);
    int iy = bin_coord(pc[n + N]);
    int iz = bin_coord(pc[n + 2 * N]);
    bool ok = (unsigned)ix < (unsigned)GW && (unsigned)iy < (unsigned)GL &&
              (unsigned)iz < (unsigned)GH;
    int v = ok ? ((ix << 12) | (iy << 6) | iz) : -1;
    vox[(size_t)b * N + n] = v;
    if (ok) rank[(size_t)b * N + n] = atomicAdd(&counts[b * GV + v], 1);
}

// Phase 2a: per-block (1024 elements) exclusive scan + block sums.
__global__ void scan_blocks_kernel(const int* __restrict__ counts,
                                   int* __restrict__ offsets,
                                   int* __restrict__ blocksums) {
    __shared__ int lds[256];
    int t = threadIdx.x;
    int base = blockIdx.x * 1024 + t * 4;
    int4 c = *(const int4*)&counts[base];
    int s0 = c.x, s1 = s0 + c.y, s2 = s1 + c.z, s3 = s2 + c.w;
    lds[t] = s3;
    __syncthreads();
    for (int d = 1; d < 256; d <<= 1) {
        int v = (t >= d) ? lds[t - d] : 0;
        __syncthreads();
        if (t >= d) lds[t] += v;
        __syncthreads();
    }
    int excl = (t > 0) ? lds[t - 1] : 0;
    int4 o;
    o.x = excl; o.y = excl + s0; o.z = excl + s1; o.w = excl + s2;
    *(int4*)&offsets[base] = o;
    if (t == 255) blocksums[blockIdx.x] = lds[255];
}

// Phase 2b: exclusive scan of the 1024 block sums (single block), in place.
__global__ void scan_sums_kernel(int* __restrict__ blocksums) {
    __shared__ int lds[256];
    int t = threadIdx.x;
    int4 c = *(const int4*)&blocksums[t * 4];
    int s0 = c.x, s1 = s0 + c.y, s2 = s1 + c.z, s3 = s2 + c.w;
    lds[t] = s3;
    __syncthreads();
    for (int d = 1; d < 256; d <<= 1) {
        int v = (t >= d) ? lds[t - d] : 0;
        __syncthreads();
        if (t >= d) lds[t] += v;
        __syncthreads();
    }
    int excl = (t > 0) ? lds[t - 1] : 0;
    int4 o;
    o.x = excl; o.y = excl + s0; o.z = excl + s1; o.w = excl + s2;
    *(int4*)&blocksums[t * 4] = o;
}

// Phase 2c: add block offsets.
__global__ void scan_add_kernel(int* __restrict__ offsets,
                                const int* __restrict__ blocksums) {
    int i = blockIdx.x * blockDim.x + threadIdx.x;   // uint4 index
    int s = blocksums[(i * 4) >> 10];
    int4 o = *(int4*)&offsets[i * 4];
    o.x += s; o.y += s; o.z += s; o.w += s;
    *(int4*)&offsets[i * 4] = o;
}

// ---------------------------------------------------------------------------
// Phase 3 (R6): sortscatter2 — full-line scattered writes via LDS transpose.
// Wave handles 64 points. Stage point rows in LDS[lane][33] (pad-33: all
// accesses <=2-way bank alias = free). Write-out: instruction s covers chunks
// q = 8s..8s+7, lane = (q-group, piece j): 8 lanes write the 8 consecutive
// float4 of chunk q -> each 128B destination line fully written by ONE
// instruction -> coalescer emits full-line writes (kills the 2.3x WRITE amp).
__global__ void sortscatter2_kernel(const float* __restrict__ attrs,
                                    const int* __restrict__ vox,
                                    const int* __restrict__ rank,
                                    const int* __restrict__ offsets,
                                    float* __restrict__ sortedT,
                                    size_t sortedStride,  // floats per batch
                                    int b0, int N) {
    __shared__ float lds[4][64 * 33];
    __shared__ int posb[4][64];
    int t = threadIdx.x;
    int w = t >> 6;
    int l = t & 63;
    int n = blockIdx.x * 256 + t;
    int b = b0 + blockIdx.y;

    int pos = -1;
    if (n < N) {
        int v = vox[(size_t)b * N + n];
        if (v >= 0) {
            int base = offsets[b * GV];   // batch region start (L2 broadcast)
            pos = offsets[b * GV + v] + rank[(size_t)b * N + n] - base;
        }
    }
    posb[w][l] = pos;

    if (n < N) {
        const float* pa = attrs + (size_t)b * 32 * N + n;
        float* row = &lds[w][l * 33];
#pragma unroll
        for (int c = 0; c < 32; ++c)
            row[c] = pa[(size_t)c * N];     // 256B coalesced per instruction
    }
    __syncthreads();

    float* dbase = sortedT + (size_t)blockIdx.y * sortedStride;
    int j = l & 7;                           // piece within chunk
#pragma unroll
    for (int s = 0; s < 8; ++s) {
        int q = s * 8 + (l >> 3);            // source lane / chunk in wave
        int p = posb[w][q];                  // LDS broadcast per 8 lanes
        if (p >= 0) {
            const float* src = &lds[w][q * 33 + j * 4];
            float4 val = make_float4(src[0], src[1], src[2], src[3]);
            *(float4*)&dbase[(size_t)p * 32 + j * 4] = val;
        }
    }
}

// Phase 4 (R6): segmax2 — cooperative segmented max.
// Block = 64 voxels. Wave w covers 16 voxels as 8 pairs; lane = (g = half,
// c = channel). Per k-iteration lanes read two full 128B segments (all lanes
// active while k < cnt); divergence = max of 2 cnts, not 64. Accumulate in
// registers, transpose through LDS (pad-33), then 256B-coalesced stores to
// the [B,C,V] layout.
__global__ void segmax2_kernel(const float* __restrict__ sortedT,
                               const int* __restrict__ counts,
                               const int* __restrict__ offsets,
                               float* __restrict__ vdata,
                               float* __restrict__ occ,
                               size_t sortedStride,  // floats per batch
                               int b0) {
    __shared__ float acc[64 * 33];
    __shared__ int cntv[64];
    int t = threadIdx.x;
    int w = t >> 6;          // wave 0..3
    int lane = t & 63;
    int g = lane >> 5;       // which voxel of the pair
    int c = lane & 31;       // channel
    int b = b0 + blockIdx.y;
    int v0 = blockIdx.x * 64;
    int batchbase = offsets[b * GV];
    const float* sbase = sortedT + (size_t)blockIdx.y * sortedStride;

#pragma unroll
    for (int pp = 0; pp < 8; ++pp) {
        int vl = w * 16 + pp * 2 + g;        // local voxel 0..63
        int bv = b * GV + v0 + vl;
        int cnt = counts[bv];                // broadcast across 32 lanes
        int off = offsets[bv] - batchbase;
        const float* src = sbase + (size_t)off * 32 + c;
        float m = -INFINITY;
        for (int k = 0; k < cnt; ++k)
            m = fmaxf(m, src[(size_t)k * 32]);
        acc[vl * 33 + c] = (cnt > 0) ? m : 0.0f;
        if (c == 0) cntv[vl] = cnt;
    }
    __syncthreads();

    int vv = v0 + lane;
#pragma unroll
    for (int cc = 0; cc < 8; ++cc) {
        int ch = cc * 4 + w;                 // wave w handles channels w,4+w,...
        vdata[(((size_t)(b * 32 + ch)) << 18) + vv] = acc[lane * 33 + ch];
    }
    if (t < 64)
        occ[b * GV + v0 + t] = (cntv[t] >= MIN_PTS) ? 1.0f : 0.0f;
}

// ---------------------------------------------------------------------------
// v1 path (R4, 451us): kept as middle tier when ws is too small for sortedT.
__global__ void scatter_idx_kernel(const int* __restrict__ vox,
                                   const int* __restrict__ rank,
                                   const int* __restrict__ offsets,
                                   int* __restrict__ sorted_idx,
                                   int N) {
    int n = blockIdx.x * blockDim.x + threadIdx.x;
    int b = blockIdx.y;
    if (n >= N) return;
    int v = vox[(size_t)b * N + n];
    if (v < 0) return;
    sorted_idx[offsets[b * GV + v] + rank[(size_t)b * N + n]] = n;
}

__global__ void segmax_kernel(const float* __restrict__ attrs,
                              const int* __restrict__ counts,
                              const int* __restrict__ offsets,
                              const int* __restrict__ sorted_idx,
                              float* __restrict__ vdata,
                              float* __restrict__ occ,
                              int N) {
    int t = blockIdx.x * blockDim.x + threadIdx.x;   // < NB*32*GV = 2^25
    int v = t & (GV - 1);
    int c = (t >> 18) & 31;
    int b = t >> 23;
    int bv = (b << 18) | v;
    int cnt = counts[bv];
    int off = offsets[bv];
    const float* row = attrs + ((size_t)(b * 32 + c)) * N;
    float m = -INFINITY;
    for (int k = 0; k < cnt; ++k) {
        m = fmaxf(m, row[sorted_idx[off + k]]);
    }
    vdata[((size_t)(b * 32 + c) << 18) | v] = (cnt > 0) ? m : 0.0f;
    if (c == 0) occ[bv] = (cnt >= MIN_PTS) ? 1.0f : 0.0f;
}

// ---------------------------------------------------------------------------
// FALLBACK PATH (R3): direct atomicMax into d_out, any C. (absmax 0, 1206us)
__device__ __forceinline__ unsigned enc_f32(float f) {
    unsigned u = __float_as_uint(f);
    return (u & 0x80000000u) ? ~u : (u | 0x80000000u);
}
__device__ __forceinline__ float dec_f32(unsigned u) {
    return (u & 0x80000000u) ? __uint_as_float(u & 0x7FFFFFFFu)
                             : __uint_as_float(~u);
}

__global__ void init_kernel(uint4* __restrict__ data4, uint4* __restrict__ cnt4,
                            int nData4, int nCnt4) {
    int i = blockIdx.x * blockDim.x + threadIdx.x;
    uint4 z = make_uint4(0u, 0u, 0u, 0u);
    if (i < nData4) data4[i] = z;
    else if (i < nData4 + nCnt4) cnt4[i - nData4] = z;
}

__global__ void scatter_kernel(const float* __restrict__ coords,
                               const float* __restrict__ attrs,
                               unsigned* __restrict__ bits,
                               int* __restrict__ counts,
                               int N, int C) {
    int n = blockIdx.x * blockDim.x + threadIdx.x;
    int b = blockIdx.y;
    if (n >= N) return;
    const float* pc = coords + (size_t)b * 3 * N;
    int ix = bin_coord(pc[n]);
    int iy = bin_coord(pc[n + N]);
    int iz = bin_coord(pc[n + 2 * N]);
    if ((unsigned)ix >= (unsigned)GW || (unsigned)iy >= (unsigned)GL ||
        (unsigned)iz >= (unsigned)GH)
        return;
    int v = (ix << 12) | (iy << 6) | iz;
    atomicAdd(&counts[b * GV + v], 1);
    const float* pa = attrs + (size_t)b * C * N + n;
    unsigned* pb = bits + (size_t)b * C * GV + v;
    for (int c = 0; c < C; ++c)
        atomicMax(&pb[(size_t)c * GV], enc_f32(pa[(size_t)c * N]));
}

__global__ void finalize_kernel(unsigned* __restrict__ data,
                                const int* __restrict__ counts,
                                float* __restrict__ occ, int C) {
    int i = blockIdx.x * blockDim.x + threadIdx.x;
    int nData4 = NB * C * GV / 4;
    int nOcc4 = NB * GV / 4;
    if (i < nData4) {
        int idx = i << 2;
        int v = idx & (GV - 1);
        int b = idx / (C * GV);
        int4 cv = *(const int4*)&counts[b * GV + v];
        uint4 u = *(const uint4*)&data[idx];
        float4 r;
        r.x = cv.x > 0 ? dec_f32(u.x) : 0.0f;
        r.y = cv.y > 0 ? dec_f32(u.y) : 0.0f;
        r.z = cv.z > 0 ? dec_f32(u.z) : 0.0f;
        r.w = cv.w > 0 ? dec_f32(u.w) : 0.0f;
        *(float4*)&data[idx] = r;
    } else if (i < nData4 + nOcc4) {
        int j = (i - nData4) << 2;
        int4 cv = *(const int4*)&counts[j];
        float4 r;
        r.x = cv.x >= MIN_PTS ? 1.0f : 0.0f;
        r.y = cv.y >= MIN_PTS ? 1.0f : 0.0f;
        r.z = cv.z >= MIN_PTS ? 1.0f : 0.0f;
        r.w = cv.w >= MIN_PTS ? 1.0f : 0.0f;
        *(float4*)&occ[j] = r;
    }
}

// ---------------------------------------------------------------------------
extern "C" void kernel_launch(void* const* d_in, const int* in_sizes, int n_in,
                              void* d_out, int out_size, void* d_ws, size_t ws_size,
                              hipStream_t stream) {
    const float* coords = (const float*)d_in[0];  // [B,3,N]
    const float* attrs  = (const float*)d_in[1];  // [B,C,N]
    int N = in_sizes[0] / (NB * 3);
    int C = in_sizes[1] / (NB * N);

    // Common ws prefix: counts[B*GV] | offsets[B*GV] | blocksums[4096]
    //                   | vox[B*N] | rank[B*N]
    size_t wsCommon = (size_t)(2 * NB * GV + 4096 + 2 * NB * N) * 4;  // ~14.8MB
    size_t oneT  = (size_t)N * 32 * 4;        // 25.6MB, sortedT for one batch
    size_t fullT = (size_t)NB * N * 32 * 4;   // 102.4MB, sortedT for all
    size_t wsV1  = wsCommon + (size_t)NB * N * 4;  // + sorted_idx (~18MB)

    if (C == 32 && ws_size >= wsCommon + oneT) {
        // ------------------- R6 path: full-line sort + cooperative segmax ---
        int* counts    = (int*)d_ws;
        int* offsets   = counts + (size_t)NB * GV;
        int* blocksums = offsets + (size_t)NB * GV;
        int* vox       = blocksums + 4096;
        int* rank      = vox + (size_t)NB * N;
        float* sortedT = (float*)(rank + (size_t)NB * N);
        float* vdata   = (float*)d_out;                       // [B,32,V]
        float* occ     = (float*)d_out + (size_t)NB * 32 * GV;

        int nCnt4 = NB * GV / 4;                              // 262144
        zero_kernel<<<(nCnt4 + 255) / 256, 256, 0, stream>>>((uint4*)counts,
                                                             nCnt4);
        dim3 pgrid((N + 255) / 256, NB);
        hist_kernel<<<pgrid, 256, 0, stream>>>(coords, counts, vox, rank, N);

        scan_blocks_kernel<<<NB * GV / 1024, 256, 0, stream>>>(counts, offsets,
                                                               blocksums);
        scan_sums_kernel<<<1, 256, 0, stream>>>(blocksums);
        scan_add_kernel<<<NB * GV / 1024, 256, 0, stream>>>(offsets, blocksums);

        if (ws_size >= wsCommon + fullT) {
            sortscatter2_kernel<<<dim3((N + 255) / 256, NB), 256, 0, stream>>>(
                attrs, vox, rank, offsets, sortedT, (size_t)N * 32, 0, N);
            segmax2_kernel<<<dim3(GV / 64, NB), 256, 0, stream>>>(
                sortedT, counts, offsets, vdata, occ, (size_t)N * 32, 0);
        } else {
            for (int b = 0; b < NB; ++b) {
                sortscatter2_kernel<<<dim3((N + 255) / 256, 1), 256, 0, stream>>>(
                    attrs, vox, rank, offsets, sortedT, 0, b, N);
                segmax2_kernel<<<dim3(GV / 64, 1), 256, 0, stream>>>(
                    sortedT, counts, offsets, vdata, occ, 0, b);
            }
        }
    } else if (C == 32 && ws_size >= wsV1) {
        // ------------------- R4 path: index sort + per-channel gather -------
        int* counts     = (int*)d_ws;
        int* offsets    = counts + (size_t)NB * GV;
        int* blocksums  = offsets + (size_t)NB * GV;
        int* vox        = blocksums + 4096;
        int* rank       = vox + (size_t)NB * N;
        int* sorted_idx = rank + (size_t)NB * N;
        float* vdata    = (float*)d_out;                      // [B,32,V]
        float* occ      = (float*)d_out + (size_t)NB * 32 * GV;

        int nCnt4 = NB * GV / 4;
        zero_kernel<<<(nCnt4 + 255) / 256, 256, 0, stream>>>((uint4*)counts,
                                                             nCnt4);
        dim3 pgrid((N + 255) / 256, NB);
        hist_kernel<<<pgrid, 256, 0, stream>>>(coords, counts, vox, rank, N);

        scan_blocks_kernel<<<NB * GV / 1024, 256, 0, stream>>>(counts, offsets,
                                                               blocksums);
        scan_sums_kernel<<<1, 256, 0, stream>>>(blocksums);
        scan_add_kernel<<<NB * GV / 1024, 256, 0, stream>>>(offsets, blocksums);

        scatter_idx_kernel<<<pgrid, 256, 0, stream>>>(vox, rank, offsets,
                                                      sorted_idx, N);

        int segThreads = NB * 32 * GV;                        // 2^25
        segmax_kernel<<<segThreads / 256, 256, 0, stream>>>(
            attrs, counts, offsets, sorted_idx, vdata, occ, N);
    } else {
        unsigned* bits = (unsigned*)d_out;
        float* occ = (float*)d_out + (size_t)NB * C * GV;
        int* counts = (int*)d_ws;
        int nData4 = NB * C * GV / 4;
        int nCnt4 = NB * GV / 4;
        int initTotal = nData4 + nCnt4;
        init_kernel<<<(initTotal + 255) / 256, 256, 0, stream>>>(
            (uint4*)d_out, (uint4*)d_ws, nData4, nCnt4);
        dim3 sgrid((N + 255) / 256, NB);
        scatter_kernel<<<sgrid, 256, 0, stream>>>(coords, attrs, bits, counts,
                                                  N, C);
        finalize_kernel<<<(initTotal + 255) / 256, 256, 0, stream>>>(
            bits, counts, occ, C);
    }
}

// Round 4
// 323.999 us; speedup vs baseline: 1.1246x; 1.0362x over previous
//
#include <hip/hip_runtime.h>
#include <math.h>

// PointcloudToVoxels: B=4, C=32, N=200k, 64^3 grid, V=262144.
// Output: [B,C,V] voxeldata (f32) then [B,1,V] occupancy (f32).
//
// R4: device-scope atomics are memory-side (~26 G/s) -> counting sort.
// R5: materialized channel-vector sort, 364us. sortscatter WRITE 237.6MB vs
//     102.4MB useful (16B-granule scatter).
// R6: full-line scattered writes (LDS transpose) + cooperative segmax, 336us.
//     Top-5 clogged by harness fills (83us) -> every kernel now <82us;
//     time is spread: ~75+75+31+15 + overhead.
// R7: split transpose from permute.
//     (a) hist_transpose: fused. Dense-coalesced transpose attrs[C,N] ->
//         attrsT[N,C] (wave writes 8KB contiguous) PLUS vox/rank/counts
//         atomics -- atomic latency hides under the 204MB stream.
//     (b) scatter_idx: the only scattered write left is 4B point-ids into a
//         3MB region (fully L2-merged).
//     (c) segmax3: cooperative (64 vox/block, lane=(pair,channel)), gathers
//         full 128B rows attrsT[idx*32..] -- scattered READS from L3-resident
//         scratch instead of scattered HBM writes. counts/offsets preloaded
//         to LDS once per block.
// R8: R7 resubmitted verbatim (R7 bench was an acquisition timeout; no data).

#define GW 64
#define GL 64
#define GH 64
#define GV (GW * GL * GH)   // 262144 = 2^18
#define NB 4
#define MIN_PTS 10

// Binning that bit-matches XLA's floor(x/0.05 + 0.5) (x/0.05 folds to
// x*20.0f exactly; __fmul_rn/__fadd_rn forbid FMA contraction). [R3: absmax 0]
__device__ __forceinline__ int bin_coord(float x) {
    float m = __fmul_rn(x, 20.0f);
    float r = __fadd_rn(m, 0.5f);
    return (int)floorf(r);
}

__global__ void zero_kernel(uint4* __restrict__ p, int n4) {
    int i = blockIdx.x * blockDim.x + threadIdx.x;
    if (i < n4) p[i] = make_uint4(0u, 0u, 0u, 0u);
}

// ---------------------------------------------------------------------------
// Phase 1 (R7): fused histogram + dense transpose.
// Each thread: bin its point (1 returning atomic) AND stage its 32 channels
// in LDS[lane][33]. Write-out: 8-lane groups emit the 8 float4 pieces of one
// point's 128B row; consecutive q -> wave writes 8KB fully contiguous.
__global__ void hist_transpose_kernel(const float* __restrict__ coords,
                                      const float* __restrict__ attrs,
                                      int* __restrict__ counts,
                                      int* __restrict__ vox,
                                      int* __restrict__ rank,
                                      float* __restrict__ attrsT,
                                      size_t strideT,  // floats per batch slot
                                      int b0, int N) {
    __shared__ float lds[4][64 * 33];
    int t = threadIdx.x;
    int w = t >> 6;
    int l = t & 63;
    int n = blockIdx.x * 256 + t;
    int b = b0 + blockIdx.y;

    if (n < N) {
        const float* pc = coords + (size_t)b * 3 * N;
        int ix = bin_coord(pc[n]);
        int iy = bin_coord(pc[n + N]);
        int iz = bin_coord(pc[n + 2 * N]);
        bool ok = (unsigned)ix < (unsigned)GW && (unsigned)iy < (unsigned)GL &&
                  (unsigned)iz < (unsigned)GH;
        int v = ok ? ((ix << 12) | (iy << 6) | iz) : -1;
        vox[(size_t)b * N + n] = v;
        if (ok) rank[(size_t)b * N + n] = atomicAdd(&counts[b * GV + v], 1);

        const float* pa = attrs + (size_t)b * 32 * N + n;
        float* row = &lds[w][l * 33];
#pragma unroll
        for (int c = 0; c < 32; ++c)
            row[c] = pa[(size_t)c * N];     // 256B coalesced per instruction
    }
    __syncthreads();

    float* dbase = attrsT + (size_t)blockIdx.y * strideT;
    int wbase = blockIdx.x * 256 + w * 64;
    int j = l & 7;                           // piece within row
#pragma unroll
    for (int s = 0; s < 8; ++s) {
        int q = s * 8 + (l >> 3);            // source lane within wave
        int p = wbase + q;                   // destination point id (dense!)
        if (p < N) {
            const float* src = &lds[w][q * 33 + j * 4];
            float4 val = make_float4(src[0], src[1], src[2], src[3]);
            *(float4*)&dbase[(size_t)p * 32 + j * 4] = val;
        }
    }
}

// Standalone hist (per-batch-scratch tier needs hist for ALL batches first).
__global__ void hist_kernel(const float* __restrict__ coords,
                            int* __restrict__ counts,
                            int* __restrict__ vox,
                            int* __restrict__ rank,
                            int N) {
    int n = blockIdx.x * blockDim.x + threadIdx.x;
    int b = blockIdx.y;
    if (n >= N) return;
    const float* pc = coords + (size_t)b * 3 * N;
    int ix = bin_coord(pc[n]);
    int iy = bin_coord(pc[n + N]);
    int iz = bin_coord(pc[n + 2 * N]);
    bool ok = (unsigned)ix < (unsigned)GW && (unsigned)iy < (unsigned)GL &&
              (unsigned)iz < (unsigned)GH;
    int v = ok ? ((ix << 12) | (iy << 6) | iz) : -1;
    vox[(size_t)b * N + n] = v;
    if (ok) rank[(size_t)b * N + n] = atomicAdd(&counts[b * GV + v], 1);
}

// Standalone dense transpose (per-batch-scratch tier).
__global__ void transpose_kernel(const float* __restrict__ attrs,
                                 float* __restrict__ attrsT,
                                 size_t strideT, int b0, int N) {
    __shared__ float lds[4][64 * 33];
    int t = threadIdx.x;
    int w = t >> 6;
    int l = t & 63;
    int n = blockIdx.x * 256 + t;
    int b = b0 + blockIdx.y;
    if (n < N) {
        const float* pa = attrs + (size_t)b * 32 * N + n;
        float* row = &lds[w][l * 33];
#pragma unroll
        for (int c = 0; c < 32; ++c)
            row[c] = pa[(size_t)c * N];
    }
    __syncthreads();
    float* dbase = attrsT + (size_t)blockIdx.y * strideT;
    int wbase = blockIdx.x * 256 + w * 64;
    int j = l & 7;
#pragma unroll
    for (int s = 0; s < 8; ++s) {
        int q = s * 8 + (l >> 3);
        int p = wbase + q;
        if (p < N) {
            const float* src = &lds[w][q * 33 + j * 4];
            float4 val = make_float4(src[0], src[1], src[2], src[3]);
            *(float4*)&dbase[(size_t)p * 32 + j * 4] = val;
        }
    }
}

// Phase 2a: per-block (1024 elements) exclusive scan + block sums.
__global__ void scan_blocks_kernel(const int* __restrict__ counts,
                                   int* __restrict__ offsets,
                                   int* __restrict__ blocksums) {
    __shared__ int lds[256];
    int t = threadIdx.x;
    int base = blockIdx.x * 1024 + t * 4;
    int4 c = *(const int4*)&counts[base];
    int s0 = c.x, s1 = s0 + c.y, s2 = s1 + c.z, s3 = s2 + c.w;
    lds[t] = s3;
    __syncthreads();
    for (int d = 1; d < 256; d <<= 1) {
        int v = (t >= d) ? lds[t - d] : 0;
        __syncthreads();
        if (t >= d) lds[t] += v;
        __syncthreads();
    }
    int excl = (t > 0) ? lds[t - 1] : 0;
    int4 o;
    o.x = excl; o.y = excl + s0; o.z = excl + s1; o.w = excl + s2;
    *(int4*)&offsets[base] = o;
    if (t == 255) blocksums[blockIdx.x] = lds[255];
}

// Phase 2b: exclusive scan of the 1024 block sums (single block), in place.
__global__ void scan_sums_kernel(int* __restrict__ blocksums) {
    __shared__ int lds[256];
    int t = threadIdx.x;
    int4 c = *(const int4*)&blocksums[t * 4];
    int s0 = c.x, s1 = s0 + c.y, s2 = s1 + c.z, s3 = s2 + c.w;
    lds[t] = s3;
    __syncthreads();
    for (int d = 1; d < 256; d <<= 1) {
        int v = (t >= d) ? lds[t - d] : 0;
        __syncthreads();
        if (t >= d) lds[t] += v;
        __syncthreads();
    }
    int excl = (t > 0) ? lds[t - 1] : 0;
    int4 o;
    o.x = excl; o.y = excl + s0; o.z = excl + s1; o.w = excl + s2;
    *(int4*)&blocksums[t * 4] = o;
}

// Phase 2c: add block offsets.
__global__ void scan_add_kernel(int* __restrict__ offsets,
                                const int* __restrict__ blocksums) {
    int i = blockIdx.x * blockDim.x + threadIdx.x;   // uint4 index
    int s = blocksums[(i * 4) >> 10];
    int4 o = *(int4*)&offsets[i * 4];
    o.x += s; o.y += s; o.z += s; o.w += s;
    *(int4*)&offsets[i * 4] = o;
}

// Phase 3: scatter point index into voxel-sorted position. 4B scattered
// writes into a 3MB region -> fully merged in L2, no line amplification.
__global__ void scatter_idx_kernel(const int* __restrict__ vox,
                                   const int* __restrict__ rank,
                                   const int* __restrict__ offsets,
                                   int* __restrict__ sorted_idx,
                                   int N) {
    int n = blockIdx.x * blockDim.x + threadIdx.x;
    int b = blockIdx.y;
    if (n >= N) return;
    int v = vox[(size_t)b * N + n];
    if (v < 0) return;
    sorted_idx[offsets[b * GV + v] + rank[(size_t)b * N + n]] = n;
}

// Phase 4 (R7): cooperative segmax via full-line gathers from attrsT.
// Block = 64 voxels; wave w covers 16 voxels as 8 pairs; lane = (g, c).
// Per k: 2 idx broadcasts + 2 full 128B line gathers (all lanes active).
// counts/offsets staged in LDS once per block. Output transposed through
// LDS (pad-33) -> 256B-coalesced stores to [B,C,V].
__global__ void segmax3_kernel(const float* __restrict__ attrsT,
                               const int* __restrict__ counts,
                               const int* __restrict__ offsets,
                               const int* __restrict__ sorted_idx,
                               float* __restrict__ vdata,
                               float* __restrict__ occ,
                               size_t strideT,  // floats per batch slot
                               int b0) {
    __shared__ float acc[64 * 33];
    __shared__ int cnt_l[64];
    __shared__ int off_l[64];
    int t = threadIdx.x;
    int w = t >> 6;          // wave 0..3
    int lane = t & 63;
    int g = lane >> 5;       // which voxel of the pair
    int c = lane & 31;       // channel
    int b = b0 + blockIdx.y;
    int v0 = blockIdx.x * 64;

    if (t < 64) {
        int bv = b * GV + v0 + t;
        cnt_l[t] = counts[bv];
        off_l[t] = offsets[bv];   // global position (cumulative over batches)
    }
    __syncthreads();

    const float* sbase = attrsT + (size_t)blockIdx.y * strideT;
#pragma unroll
    for (int pp = 0; pp < 8; ++pp) {
        int vl = w * 16 + pp * 2 + g;        // local voxel 0..63
        int cnt = cnt_l[vl];
        int off = off_l[vl];
        float m = -INFINITY;
        for (int k = 0; k < cnt; ++k) {
            int idx = sorted_idx[off + k];   // broadcast across 32 lanes
            m = fmaxf(m, sbase[(size_t)idx * 32 + c]);
        }
        acc[vl * 33 + c] = (cnt > 0) ? m : 0.0f;
    }
    __syncthreads();

    int vv = v0 + lane;
#pragma unroll
    for (int cc = 0; cc < 8; ++cc) {
        int ch = cc * 4 + w;                 // wave w handles channels w,4+w,...
        vdata[(((size_t)(b * 32 + ch)) << 18) + vv] = acc[lane * 33 + ch];
    }
    if (t < 64)
        occ[b * GV + v0 + t] = (cnt_l[t] >= MIN_PTS) ? 1.0f : 0.0f;
}

// ---------------------------------------------------------------------------
// v1 path (R4, 451us): middle tier when ws is too small for attrsT.
__global__ void segmax_kernel(const float* __restrict__ attrs,
                              const int* __restrict__ counts,
                              const int* __restrict__ offsets,
                              const int* __restrict__ sorted_idx,
                              float* __restrict__ vdata,
                              float* __restrict__ occ,
                              int N) {
    int t = blockIdx.x * blockDim.x + threadIdx.x;   // < NB*32*GV = 2^25
    int v = t & (GV - 1);
    int c = (t >> 18) & 31;
    int b = t >> 23;
    int bv = (b << 18) | v;
    int cnt = counts[bv];
    int off = offsets[bv];
    const float* row = attrs + ((size_t)(b * 32 + c)) * N;
    float m = -INFINITY;
    for (int k = 0; k < cnt; ++k) {
        m = fmaxf(m, row[sorted_idx[off + k]]);
    }
    vdata[((size_t)(b * 32 + c) << 18) | v] = (cnt > 0) ? m : 0.0f;
    if (c == 0) occ[bv] = (cnt >= MIN_PTS) ? 1.0f : 0.0f;
}

// ---------------------------------------------------------------------------
// FALLBACK PATH (R3): direct atomicMax into d_out, any C. (absmax 0, 1206us)
__device__ __forceinline__ unsigned enc_f32(float f) {
    unsigned u = __float_as_uint(f);
    return (u & 0x80000000u) ? ~u : (u | 0x80000000u);
}
__device__ __forceinline__ float dec_f32(unsigned u) {
    return (u & 0x80000000u) ? __uint_as_float(u & 0x7FFFFFFFu)
                             : __uint_as_float(~u);
}

__global__ void init_kernel(uint4* __restrict__ data4, uint4* __restrict__ cnt4,
                            int nData4, int nCnt4) {
    int i = blockIdx.x * blockDim.x + threadIdx.x;
    uint4 z = make_uint4(0u, 0u, 0u, 0u);
    if (i < nData4) data4[i] = z;
    else if (i < nData4 + nCnt4) cnt4[i - nData4] = z;
}

__global__ void scatter_kernel(const float* __restrict__ coords,
                               const float* __restrict__ attrs,
                               unsigned* __restrict__ bits,
                               int* __restrict__ counts,
                               int N, int C) {
    int n = blockIdx.x * blockDim.x + threadIdx.x;
    int b = blockIdx.y;
    if (n >= N) return;
    const float* pc = coords + (size_t)b * 3 * N;
    int ix = bin_coord(pc[n]);
    int iy = bin_coord(pc[n + N]);
    int iz = bin_coord(pc[n + 2 * N]);
    if ((unsigned)ix >= (unsigned)GW || (unsigned)iy >= (unsigned)GL ||
        (unsigned)iz >= (unsigned)GH)
        return;
    int v = (ix << 12) | (iy << 6) | iz;
    atomicAdd(&counts[b * GV + v], 1);
    const float* pa = attrs + (size_t)b * C * N + n;
    unsigned* pb = bits + (size_t)b * C * GV + v;
    for (int c = 0; c < C; ++c)
        atomicMax(&pb[(size_t)c * GV], enc_f32(pa[(size_t)c * N]));
}

__global__ void finalize_kernel(unsigned* __restrict__ data,
                                const int* __restrict__ counts,
                                float* __restrict__ occ, int C) {
    int i = blockIdx.x * blockDim.x + threadIdx.x;
    int nData4 = NB * C * GV / 4;
    int nOcc4 = NB * GV / 4;
    if (i < nData4) {
        int idx = i << 2;
        int v = idx & (GV - 1);
        int b = idx / (C * GV);
        int4 cv = *(const int4*)&counts[b * GV + v];
        uint4 u = *(const uint4*)&data[idx];
        float4 r;
        r.x = cv.x > 0 ? dec_f32(u.x) : 0.0f;
        r.y = cv.y > 0 ? dec_f32(u.y) : 0.0f;
        r.z = cv.z > 0 ? dec_f32(u.z) : 0.0f;
        r.w = cv.w > 0 ? dec_f32(u.w) : 0.0f;
        *(float4*)&data[idx] = r;
    } else if (i < nData4 + nOcc4) {
        int j = (i - nData4) << 2;
        int4 cv = *(const int4*)&counts[j];
        float4 r;
        r.x = cv.x >= MIN_PTS ? 1.0f : 0.0f;
        r.y = cv.y >= MIN_PTS ? 1.0f : 0.0f;
        r.z = cv.z >= MIN_PTS ? 1.0f : 0.0f;
        r.w = cv.w >= MIN_PTS ? 1.0f : 0.0f;
        *(float4*)&occ[j] = r;
    }
}

// ---------------------------------------------------------------------------
extern "C" void kernel_launch(void* const* d_in, const int* in_sizes, int n_in,
                              void* d_out, int out_size, void* d_ws, size_t ws_size,
                              hipStream_t stream) {
    const float* coords = (const float*)d_in[0];  // [B,3,N]
    const float* attrs  = (const float*)d_in[1];  // [B,C,N]
    int N = in_sizes[0] / (NB * 3);
    int C = in_sizes[1] / (NB * N);

    // ws prefix: counts[B*GV] | offsets[B*GV] | blocksums[4096]
    //            | vox[B*N] | rank[B*N] | sorted_idx[B*N]
    size_t wsCommon = (size_t)(2 * NB * GV + 4096 + 3 * NB * N) * 4;  // ~18MB
    size_t oneT  = (size_t)N * 32 * 4;        // 25.6MB, attrsT for one batch
    size_t fullT = (size_t)NB * N * 32 * 4;   // 102.4MB, attrsT for all

    if (C == 32 && ws_size >= wsCommon + oneT) {
        // ------------------- R7 path: dense transpose + line-gather segmax --
        int* counts     = (int*)d_ws;
        int* offsets    = counts + (size_t)NB * GV;
        int* blocksums  = offsets + (size_t)NB * GV;
        int* vox        = blocksums + 4096;
        int* rank       = vox + (size_t)NB * N;
        int* sorted_idx = rank + (size_t)NB * N;
        float* attrsT   = (float*)(sorted_idx + (size_t)NB * N);
        float* vdata    = (float*)d_out;                      // [B,32,V]
        float* occ      = (float*)d_out + (size_t)NB * 32 * GV;

        int nCnt4 = NB * GV / 4;                              // 262144
        zero_kernel<<<(nCnt4 + 255) / 256, 256, 0, stream>>>((uint4*)counts,
                                                             nCnt4);
        dim3 pgrid((N + 255) / 256, NB);
        bool full = (ws_size >= wsCommon + fullT);

        if (full) {
            // Fused: atomic latency hides under the 204MB transpose stream.
            hist_transpose_kernel<<<pgrid, 256, 0, stream>>>(
                coords, attrs, counts, vox, rank, attrsT, (size_t)N * 32, 0, N);
        } else {
            hist_kernel<<<pgrid, 256, 0, stream>>>(coords, counts, vox, rank,
                                                   N);
        }

        scan_blocks_kernel<<<NB * GV / 1024, 256, 0, stream>>>(counts, offsets,
                                                               blocksums);
        scan_sums_kernel<<<1, 256, 0, stream>>>(blocksums);
        scan_add_kernel<<<NB * GV / 1024, 256, 0, stream>>>(offsets, blocksums);

        scatter_idx_kernel<<<pgrid, 256, 0, stream>>>(vox, rank, offsets,
                                                      sorted_idx, N);

        if (full) {
            segmax3_kernel<<<dim3(GV / 64, NB), 256, 0, stream>>>(
                attrsT, counts, offsets, sorted_idx, vdata, occ,
                (size_t)N * 32, 0);
        } else {
            for (int b = 0; b < NB; ++b) {
                transpose_kernel<<<dim3((N + 255) / 256, 1), 256, 0, stream>>>(
                    attrs, attrsT, 0, b, N);
                segmax3_kernel<<<dim3(GV / 64, 1), 256, 0, stream>>>(
                    attrsT, counts, offsets, sorted_idx, vdata, occ, 0, b);
            }
        }
    } else if (C == 32 &&
               ws_size >= (size_t)(2 * NB * GV + 4096 + 3 * NB * N) * 4) {
        // ------------------- R4 path: index sort + per-channel gather -------
        int* counts     = (int*)d_ws;
        int* offsets    = counts + (size_t)NB * GV;
        int* blocksums  = offsets + (size_t)NB * GV;
        int* vox        = blocksums + 4096;
        int* rank       = vox + (size_t)NB * N;
        int* sorted_idx = rank + (size_t)NB * N;
        float* vdata    = (float*)d_out;                      // [B,32,V]
        float* occ      = (float*)d_out + (size_t)NB * 32 * GV;

        int nCnt4 = NB * GV / 4;
        zero_kernel<<<(nCnt4 + 255) / 256, 256, 0, stream>>>((uint4*)counts,
                                                             nCnt4);
        dim3 pgrid((N + 255) / 256, NB);
        hist_kernel<<<pgrid, 256, 0, stream>>>(coords, counts, vox, rank, N);

        scan_blocks_kernel<<<NB * GV / 1024, 256, 0, stream>>>(counts, offsets,
                                                               blocksums);
        scan_sums_kernel<<<1, 256, 0, stream>>>(blocksums);
        scan_add_kernel<<<NB * GV / 1024, 256, 0, stream>>>(offsets, blocksums);

        scatter_idx_kernel<<<pgrid, 256, 0, stream>>>(vox, rank, offsets,
                                                      sorted_idx, N);

        int segThreads = NB * 32 * GV;                        // 2^25
        segmax_kernel<<<segThreads / 256, 256, 0, stream>>>(
            attrs, counts, offsets, sorted_idx, vdata, occ, N);
    } else {
        unsigned* bits = (unsigned*)d_out;
        float* occ = (float*)d_out + (size_t)NB * C * GV;
        int* counts = (int*)d_ws;
        int nData4 = NB * C * GV / 4;
        int nCnt4 = NB * GV / 4;
        int initTotal = nData4 + nCnt4;
        init_kernel<<<(initTotal + 255) / 256, 256, 0, stream>>>(
            (uint4*)d_out, (uint4*)d_ws, nData4, nCnt4);
        dim3 sgrid((N + 255) / 256, NB);
        scatter_kernel<<<sgrid, 256, 0, stream>>>(coords, attrs, bits, counts,
                                                  N, C);
        finalize_kernel<<<(initTotal + 255) / 256, 256, 0, stream>>>(
            bits, counts, occ, C);
    }
}

// Round 5
// 300.522 us; speedup vs baseline: 1.2125x; 1.0781x over previous
//
#include <hip/hip_runtime.h>
#include <math.h>

// PointcloudToVoxels: B=4, C=32, N=200k, 64^3 grid, V=262144.
// Output: [B,C,V] voxeldata (f32) then [B,1,V] occupancy (f32).
//
// R4: device-scope atomics are memory-side (~26 G/s) -> counting sort.
// R5: materialized channel-vector sort, 364us. sortscatter WRITE 237.6MB vs
//     102.4MB useful (16B-granule scatter).
// R6: full-line scattered writes (LDS transpose) + cooperative segmax, 336us.
// R7/R8: dense transpose + line-gather segmax, 324us. LESSON: scattered-read
//     and scattered-write cost the same (~2.4 TB/s for random 128B lines vs
//     6.6 TB/s streaming) -- the 102MB permutation is ~40us either way.
// R9: segmax4. Two structural fixes to the gather phase:
//     (a) a block's 64 consecutive voxels own a CONTIGUOUS sorted_idx range
//         (~49 entries): stage it into LDS in one coalesced burst (chunked
//         x512) -- the per-k global idx load chain becomes an LDS read.
//     (b) lane = (voxel-octet, float4-piece): one wave-instruction gathers
//         8 voxels x 16B = 1KB (vs 2 x 128B before), 4x wider loads.

#define GW 64
#define GL 64
#define GH 64
#define GV (GW * GL * GH)   // 262144 = 2^18
#define NB 4
#define MIN_PTS 10

// Binning that bit-matches XLA's floor(x/0.05 + 0.5) (x/0.05 folds to
// x*20.0f exactly; __fmul_rn/__fadd_rn forbid FMA contraction). [R3: absmax 0]
__device__ __forceinline__ int bin_coord(float x) {
    float m = __fmul_rn(x, 20.0f);
    float r = __fadd_rn(m, 0.5f);
    return (int)floorf(r);
}

__global__ void zero_kernel(uint4* __restrict__ p, int n4) {
    int i = blockIdx.x * blockDim.x + threadIdx.x;
    if (i < n4) p[i] = make_uint4(0u, 0u, 0u, 0u);
}

// ---------------------------------------------------------------------------
// Phase 1 (R7): fused histogram + dense transpose.
// Each thread: bin its point (1 returning atomic) AND stage its 32 channels
// in LDS[lane][33]. Write-out: 8-lane groups emit the 8 float4 pieces of one
// point's 128B row; consecutive q -> wave writes 8KB fully contiguous.
__global__ void hist_transpose_kernel(const float* __restrict__ coords,
                                      const float* __restrict__ attrs,
                                      int* __restrict__ counts,
                                      int* __restrict__ vox,
                                      int* __restrict__ rank,
                                      float* __restrict__ attrsT,
                                      size_t strideT,  // floats per batch slot
                                      int b0, int N) {
    __shared__ float lds[4][64 * 33];
    int t = threadIdx.x;
    int w = t >> 6;
    int l = t & 63;
    int n = blockIdx.x * 256 + t;
    int b = b0 + blockIdx.y;

    if (n < N) {
        const float* pc = coords + (size_t)b * 3 * N;
        int ix = bin_coord(pc[n]);
        int iy = bin_coord(pc[n + N]);
        int iz = bin_coord(pc[n + 2 * N]);
        bool ok = (unsigned)ix < (unsigned)GW && (unsigned)iy < (unsigned)GL &&
                  (unsigned)iz < (unsigned)GH;
        int v = ok ? ((ix << 12) | (iy << 6) | iz) : -1;
        vox[(size_t)b * N + n] = v;
        if (ok) rank[(size_t)b * N + n] = atomicAdd(&counts[b * GV + v], 1);

        const float* pa = attrs + (size_t)b * 32 * N + n;
        float* row = &lds[w][l * 33];
#pragma unroll
        for (int c = 0; c < 32; ++c)
            row[c] = pa[(size_t)c * N];     // 256B coalesced per instruction
    }
    __syncthreads();

    float* dbase = attrsT + (size_t)blockIdx.y * strideT;
    int wbase = blockIdx.x * 256 + w * 64;
    int j = l & 7;                           // piece within row
#pragma unroll
    for (int s = 0; s < 8; ++s) {
        int q = s * 8 + (l >> 3);            // source lane within wave
        int p = wbase + q;                   // destination point id (dense!)
        if (p < N) {
            const float* src = &lds[w][q * 33 + j * 4];
            float4 val = make_float4(src[0], src[1], src[2], src[3]);
            *(float4*)&dbase[(size_t)p * 32 + j * 4] = val;
        }
    }
}

// Standalone hist (per-batch-scratch tier needs hist for ALL batches first).
__global__ void hist_kernel(const float* __restrict__ coords,
                            int* __restrict__ counts,
                            int* __restrict__ vox,
                            int* __restrict__ rank,
                            int N) {
    int n = blockIdx.x * blockDim.x + threadIdx.x;
    int b = blockIdx.y;
    if (n >= N) return;
    const float* pc = coords + (size_t)b * 3 * N;
    int ix = bin_coord(pc[n]);
    int iy = bin_coord(pc[n + N]);
    int iz = bin_coord(pc[n + 2 * N]);
    bool ok = (unsigned)ix < (unsigned)GW && (unsigned)iy < (unsigned)GL &&
              (unsigned)iz < (unsigned)GH;
    int v = ok ? ((ix << 12) | (iy << 6) | iz) : -1;
    vox[(size_t)b * N + n] = v;
    if (ok) rank[(size_t)b * N + n] = atomicAdd(&counts[b * GV + v], 1);
}

// Standalone dense transpose (per-batch-scratch tier).
__global__ void transpose_kernel(const float* __restrict__ attrs,
                                 float* __restrict__ attrsT,
                                 size_t strideT, int b0, int N) {
    __shared__ float lds[4][64 * 33];
    int t = threadIdx.x;
    int w = t >> 6;
    int l = t & 63;
    int n = blockIdx.x * 256 + t;
    int b = b0 + blockIdx.y;
    if (n < N) {
        const float* pa = attrs + (size_t)b * 32 * N + n;
        float* row = &lds[w][l * 33];
#pragma unroll
        for (int c = 0; c < 32; ++c)
            row[c] = pa[(size_t)c * N];
    }
    __syncthreads();
    float* dbase = attrsT + (size_t)blockIdx.y * strideT;
    int wbase = blockIdx.x * 256 + w * 64;
    int j = l & 7;
#pragma unroll
    for (int s = 0; s < 8; ++s) {
        int q = s * 8 + (l >> 3);
        int p = wbase + q;
        if (p < N) {
            const float* src = &lds[w][q * 33 + j * 4];
            float4 val = make_float4(src[0], src[1], src[2], src[3]);
            *(float4*)&dbase[(size_t)p * 32 + j * 4] = val;
        }
    }
}

// Phase 2a: per-block (1024 elements) exclusive scan + block sums.
__global__ void scan_blocks_kernel(const int* __restrict__ counts,
                                   int* __restrict__ offsets,
                                   int* __restrict__ blocksums) {
    __shared__ int lds[256];
    int t = threadIdx.x;
    int base = blockIdx.x * 1024 + t * 4;
    int4 c = *(const int4*)&counts[base];
    int s0 = c.x, s1 = s0 + c.y, s2 = s1 + c.z, s3 = s2 + c.w;
    lds[t] = s3;
    __syncthreads();
    for (int d = 1; d < 256; d <<= 1) {
        int v = (t >= d) ? lds[t - d] : 0;
        __syncthreads();
        if (t >= d) lds[t] += v;
        __syncthreads();
    }
    int excl = (t > 0) ? lds[t - 1] : 0;
    int4 o;
    o.x = excl; o.y = excl + s0; o.z = excl + s1; o.w = excl + s2;
    *(int4*)&offsets[base] = o;
    if (t == 255) blocksums[blockIdx.x] = lds[255];
}

// Phase 2b: exclusive scan of the 1024 block sums (single block), in place.
__global__ void scan_sums_kernel(int* __restrict__ blocksums) {
    __shared__ int lds[256];
    int t = threadIdx.x;
    int4 c = *(const int4*)&blocksums[t * 4];
    int s0 = c.x, s1 = s0 + c.y, s2 = s1 + c.z, s3 = s2 + c.w;
    lds[t] = s3;
    __syncthreads();
    for (int d = 1; d < 256; d <<= 1) {
        int v = (t >= d) ? lds[t - d] : 0;
        __syncthreads();
        if (t >= d) lds[t] += v;
        __syncthreads();
    }
    int excl = (t > 0) ? lds[t - 1] : 0;
    int4 o;
    o.x = excl; o.y = excl + s0; o.z = excl + s1; o.w = excl + s2;
    *(int4*)&blocksums[t * 4] = o;
}

// Phase 2c: add block offsets.
__global__ void scan_add_kernel(int* __restrict__ offsets,
                                const int* __restrict__ blocksums) {
    int i = blockIdx.x * blockDim.x + threadIdx.x;   // uint4 index
    int s = blocksums[(i * 4) >> 10];
    int4 o = *(int4*)&offsets[i * 4];
    o.x += s; o.y += s; o.z += s; o.w += s;
    *(int4*)&offsets[i * 4] = o;
}

// Phase 3: scatter point index into voxel-sorted position. 4B scattered
// writes into a 3MB region -> fully merged in L2, no line amplification.
__global__ void scatter_idx_kernel(const int* __restrict__ vox,
                                   const int* __restrict__ rank,
                                   const int* __restrict__ offsets,
                                   int* __restrict__ sorted_idx,
                                   int N) {
    int n = blockIdx.x * blockDim.x + threadIdx.x;
    int b = blockIdx.y;
    if (n >= N) return;
    int v = vox[(size_t)b * N + n];
    if (v < 0) return;
    sorted_idx[offsets[b * GV + v] + rank[(size_t)b * N + n]] = n;
}

// Phase 4 (R9): segmax4 — LDS-staged idx + octet float4 gathers.
// Block = 64 consecutive voxels; their sorted_idx entries form ONE contiguous
// range [off0, off0+npts). Stage it into LDS (chunks of 512, coalesced).
// Lane = (vo = voxel-in-octet, j = float4 piece): per k-step each active lane
// gathers float4 -> one wave-instruction moves up to 8 voxels x 16B = 1KB.
// Accumulate 2 octets x 4 channels in registers (static indexing); pad-33 LDS
// transpose -> 256B-coalesced stores to [B,C,V].
__global__ void segmax4_kernel(const float* __restrict__ attrsT,
                               const int* __restrict__ counts,
                               const int* __restrict__ offsets,
                               const int* __restrict__ sorted_idx,
                               float* __restrict__ vdata,
                               float* __restrict__ occ,
                               size_t strideT,  // floats per batch slot
                               int b0) {
    __shared__ float acc[64 * 33];
    __shared__ int cnt_l[64];
    __shared__ int off_l[64];
    __shared__ int sidx[512];
    int t = threadIdx.x;
    int w = t >> 6;          // wave 0..3
    int l = t & 63;
    int vo = l >> 3;         // voxel within octet (0..7)
    int j = l & 7;           // float4 piece (0..7) -> channels 4j..4j+3
    int b = b0 + blockIdx.y;
    int v0 = blockIdx.x * 64;

    if (t < 64) {
        int bv = b * GV + v0 + t;
        cnt_l[t] = counts[bv];
        off_l[t] = offsets[bv];
    }
    __syncthreads();
    int off0 = off_l[0];
    int npts = off_l[63] + cnt_l[63] - off0;

    // this lane's two voxels (octet 0 and 1 of its wave's 16)
    int vl0 = w * 16 + vo;
    int vl1 = w * 16 + 8 + vo;
    int ks0 = off_l[vl0] - off0, ke0 = ks0 + cnt_l[vl0];
    int ks1 = off_l[vl1] - off0, ke1 = ks1 + cnt_l[vl1];

    float4 m0 = make_float4(-INFINITY, -INFINITY, -INFINITY, -INFINITY);
    float4 m1 = m0;
    const float* sbase = attrsT + (size_t)blockIdx.y * strideT;
    const int* sgl = sorted_idx + off0;

    for (int base = 0; base < npts; base += 512) {
        __syncthreads();                       // protect sidx reuse
        int mm = npts - base; if (mm > 512) mm = 512;
        for (int i = t; i < mm; i += 256) sidx[i] = sgl[base + i];
        __syncthreads();
        int hi = base + mm;
        int lo0 = ks0 > base ? ks0 : base, h0 = ke0 < hi ? ke0 : hi;
        for (int k = lo0; k < h0; ++k) {
            int idx = sidx[k - base];          // LDS broadcast per 8 lanes
            float4 x = *(const float4*)&sbase[(size_t)idx * 32 + j * 4];
            m0.x = fmaxf(m0.x, x.x); m0.y = fmaxf(m0.y, x.y);
            m0.z = fmaxf(m0.z, x.z); m0.w = fmaxf(m0.w, x.w);
        }
        int lo1 = ks1 > base ? ks1 : base, h1 = ke1 < hi ? ke1 : hi;
        for (int k = lo1; k < h1; ++k) {
            int idx = sidx[k - base];
            float4 x = *(const float4*)&sbase[(size_t)idx * 32 + j * 4];
            m1.x = fmaxf(m1.x, x.x); m1.y = fmaxf(m1.y, x.y);
            m1.z = fmaxf(m1.z, x.z); m1.w = fmaxf(m1.w, x.w);
        }
    }

    // each (vl, channel) cell written by exactly one lane -> no init needed
    int c4 = j * 4;
    bool nz0 = cnt_l[vl0] > 0, nz1 = cnt_l[vl1] > 0;
    acc[vl0 * 33 + c4 + 0] = nz0 ? m0.x : 0.0f;
    acc[vl0 * 33 + c4 + 1] = nz0 ? m0.y : 0.0f;
    acc[vl0 * 33 + c4 + 2] = nz0 ? m0.z : 0.0f;
    acc[vl0 * 33 + c4 + 3] = nz0 ? m0.w : 0.0f;
    acc[vl1 * 33 + c4 + 0] = nz1 ? m1.x : 0.0f;
    acc[vl1 * 33 + c4 + 1] = nz1 ? m1.y : 0.0f;
    acc[vl1 * 33 + c4 + 2] = nz1 ? m1.z : 0.0f;
    acc[vl1 * 33 + c4 + 3] = nz1 ? m1.w : 0.0f;
    __syncthreads();

    int vv = v0 + l;
#pragma unroll
    for (int cc = 0; cc < 8; ++cc) {
        int ch = cc * 4 + w;                 // wave w handles channels w,4+w,...
        vdata[(((size_t)(b * 32 + ch)) << 18) + vv] = acc[l * 33 + ch];
    }
    if (t < 64)
        occ[b * GV + v0 + t] = (cnt_l[t] >= MIN_PTS) ? 1.0f : 0.0f;
}

// ---------------------------------------------------------------------------
// v1 path (R4, 451us): middle tier when ws is too small for attrsT.
__global__ void segmax_kernel(const float* __restrict__ attrs,
                              const int* __restrict__ counts,
                              const int* __restrict__ offsets,
                              const int* __restrict__ sorted_idx,
                              float* __restrict__ vdata,
                              float* __restrict__ occ,
                              int N) {
    int t = blockIdx.x * blockDim.x + threadIdx.x;   // < NB*32*GV = 2^25
    int v = t & (GV - 1);
    int c = (t >> 18) & 31;
    int b = t >> 23;
    int bv = (b << 18) | v;
    int cnt = counts[bv];
    int off = offsets[bv];
    const float* row = attrs + ((size_t)(b * 32 + c)) * N;
    float m = -INFINITY;
    for (int k = 0; k < cnt; ++k) {
        m = fmaxf(m, row[sorted_idx[off + k]]);
    }
    vdata[((size_t)(b * 32 + c) << 18) | v] = (cnt > 0) ? m : 0.0f;
    if (c == 0) occ[bv] = (cnt >= MIN_PTS) ? 1.0f : 0.0f;
}

// ---------------------------------------------------------------------------
// FALLBACK PATH (R3): direct atomicMax into d_out, any C. (absmax 0, 1206us)
__device__ __forceinline__ unsigned enc_f32(float f) {
    unsigned u = __float_as_uint(f);
    return (u & 0x80000000u) ? ~u : (u | 0x80000000u);
}
__device__ __forceinline__ float dec_f32(unsigned u) {
    return (u & 0x80000000u) ? __uint_as_float(u & 0x7FFFFFFFu)
                             : __uint_as_float(~u);
}

__global__ void init_kernel(uint4* __restrict__ data4, uint4* __restrict__ cnt4,
                            int nData4, int nCnt4) {
    int i = blockIdx.x * blockDim.x + threadIdx.x;
    uint4 z = make_uint4(0u, 0u, 0u, 0u);
    if (i < nData4) data4[i] = z;
    else if (i < nData4 + nCnt4) cnt4[i - nData4] = z;
}

__global__ void scatter_kernel(const float* __restrict__ coords,
                               const float* __restrict__ attrs,
                               unsigned* __restrict__ bits,
                               int* __restrict__ counts,
                               int N, int C) {
    int n = blockIdx.x * blockDim.x + threadIdx.x;
    int b = blockIdx.y;
    if (n >= N) return;
    const float* pc = coords + (size_t)b * 3 * N;
    int ix = bin_coord(pc[n]);
    int iy = bin_coord(pc[n + N]);
    int iz = bin_coord(pc[n + 2 * N]);
    if ((unsigned)ix >= (unsigned)GW || (unsigned)iy >= (unsigned)GL ||
        (unsigned)iz >= (unsigned)GH)
        return;
    int v = (ix << 12) | (iy << 6) | iz;
    atomicAdd(&counts[b * GV + v], 1);
    const float* pa = attrs + (size_t)b * C * N + n;
    unsigned* pb = bits + (size_t)b * C * GV + v;
    for (int c = 0; c < C; ++c)
        atomicMax(&pb[(size_t)c * GV], enc_f32(pa[(size_t)c * N]));
}

__global__ void finalize_kernel(unsigned* __restrict__ data,
                                const int* __restrict__ counts,
                                float* __restrict__ occ, int C) {
    int i = blockIdx.x * blockDim.x + threadIdx.x;
    int nData4 = NB * C * GV / 4;
    int nOcc4 = NB * GV / 4;
    if (i < nData4) {
        int idx = i << 2;
        int v = idx & (GV - 1);
        int b = idx / (C * GV);
        int4 cv = *(const int4*)&counts[b * GV + v];
        uint4 u = *(const uint4*)&data[idx];
        float4 r;
        r.x = cv.x > 0 ? dec_f32(u.x) : 0.0f;
        r.y = cv.y > 0 ? dec_f32(u.y) : 0.0f;
        r.z = cv.z > 0 ? dec_f32(u.z) : 0.0f;
        r.w = cv.w > 0 ? dec_f32(u.w) : 0.0f;
        *(float4*)&data[idx] = r;
    } else if (i < nData4 + nOcc4) {
        int j = (i - nData4) << 2;
        int4 cv = *(const int4*)&counts[j];
        float4 r;
        r.x = cv.x >= MIN_PTS ? 1.0f : 0.0f;
        r.y = cv.y >= MIN_PTS ? 1.0f : 0.0f;
        r.z = cv.z >= MIN_PTS ? 1.0f : 0.0f;
        r.w = cv.w >= MIN_PTS ? 1.0f : 0.0f;
        *(float4*)&occ[j] = r;
    }
}

// ---------------------------------------------------------------------------
extern "C" void kernel_launch(void* const* d_in, const int* in_sizes, int n_in,
                              void* d_out, int out_size, void* d_ws, size_t ws_size,
                              hipStream_t stream) {
    const float* coords = (const float*)d_in[0];  // [B,3,N]
    const float* attrs  = (const float*)d_in[1];  // [B,C,N]
    int N = in_sizes[0] / (NB * 3);
    int C = in_sizes[1] / (NB * N);

    // ws prefix: counts[B*GV] | offsets[B*GV] | blocksums[4096]
    //            | vox[B*N] | rank[B*N] | sorted_idx[B*N]
    size_t wsCommon = (size_t)(2 * NB * GV + 4096 + 3 * NB * N) * 4;  // ~18MB
    size_t oneT  = (size_t)N * 32 * 4;        // 25.6MB, attrsT for one batch
    size_t fullT = (size_t)NB * N * 32 * 4;   // 102.4MB, attrsT for all

    if (C == 32 && ws_size >= wsCommon + oneT) {
        // ------------------- R9 path: dense transpose + octet-gather segmax -
        int* counts     = (int*)d_ws;
        int* offsets    = counts + (size_t)NB * GV;
        int* blocksums  = offsets + (size_t)NB * GV;
        int* vox        = blocksums + 4096;
        int* rank       = vox + (size_t)NB * N;
        int* sorted_idx = rank + (size_t)NB * N;
        float* attrsT   = (float*)(sorted_idx + (size_t)NB * N);
        float* vdata    = (float*)d_out;                      // [B,32,V]
        float* occ      = (float*)d_out + (size_t)NB * 32 * GV;

        int nCnt4 = NB * GV / 4;                              // 262144
        zero_kernel<<<(nCnt4 + 255) / 256, 256, 0, stream>>>((uint4*)counts,
                                                             nCnt4);
        dim3 pgrid((N + 255) / 256, NB);
        bool full = (ws_size >= wsCommon + fullT);

        if (full) {
            // Fused: atomic latency hides under the 204MB transpose stream.
            hist_transpose_kernel<<<pgrid, 256, 0, stream>>>(
                coords, attrs, counts, vox, rank, attrsT, (size_t)N * 32, 0, N);
        } else {
            hist_kernel<<<pgrid, 256, 0, stream>>>(coords, counts, vox, rank,
                                                   N);
        }

        scan_blocks_kernel<<<NB * GV / 1024, 256, 0, stream>>>(counts, offsets,
                                                               blocksums);
        scan_sums_kernel<<<1, 256, 0, stream>>>(blocksums);
        scan_add_kernel<<<NB * GV / 1024, 256, 0, stream>>>(offsets, blocksums);

        scatter_idx_kernel<<<pgrid, 256, 0, stream>>>(vox, rank, offsets,
                                                      sorted_idx, N);

        if (full) {
            segmax4_kernel<<<dim3(GV / 64, NB), 256, 0, stream>>>(
                attrsT, counts, offsets, sorted_idx, vdata, occ,
                (size_t)N * 32, 0);
        } else {
            for (int b = 0; b < NB; ++b) {
                transpose_kernel<<<dim3((N + 255) / 256, 1), 256, 0, stream>>>(
                    attrs, attrsT, 0, b, N);
                segmax4_kernel<<<dim3(GV / 64, 1), 256, 0, stream>>>(
                    attrsT, counts, offsets, sorted_idx, vdata, occ, 0, b);
            }
        }
    } else if (C == 32 &&
               ws_size >= (size_t)(2 * NB * GV + 4096 + 3 * NB * N) * 4) {
        // ------------------- R4 path: index sort + per-channel gather -------
        int* counts     = (int*)d_ws;
        int* offsets    = counts + (size_t)NB * GV;
        int* blocksums  = offsets + (size_t)NB * GV;
        int* vox        = blocksums + 4096;
        int* rank       = vox + (size_t)NB * N;
        int* sorted_idx = rank + (size_t)NB * N;
        float* vdata    = (float*)d_out;                      // [B,32,V]
        float* occ      = (float*)d_out + (size_t)NB * 32 * GV;

        int nCnt4 = NB * GV / 4;
        zero_kernel<<<(nCnt4 + 255) / 256, 256, 0, stream>>>((uint4*)counts,
                                                             nCnt4);
        dim3 pgrid((N + 255) / 256, NB);
        hist_kernel<<<pgrid, 256, 0, stream>>>(coords, counts, vox, rank, N);

        scan_blocks_kernel<<<NB * GV / 1024, 256, 0, stream>>>(counts, offsets,
                                                               blocksums);
        scan_sums_kernel<<<1, 256, 0, stream>>>(blocksums);
        scan_add_kernel<<<NB * GV / 1024, 256, 0, stream>>>(offsets, blocksums);

        scatter_idx_kernel<<<pgrid, 256, 0, stream>>>(vox, rank, offsets,
                                                      sorted_idx, N);

        int segThreads = NB * 32 * GV;                        // 2^25
        segmax_kernel<<<segThreads / 256, 256, 0, stream>>>(
            attrs, counts, offsets, sorted_idx, vdata, occ, N);
    } else {
        unsigned* bits = (unsigned*)d_out;
        float* occ = (float*)d_out + (size_t)NB * C * GV;
        int* counts = (int*)d_ws;
        int nData4 = NB * C * GV / 4;
        int nCnt4 = NB * GV / 4;
        int initTotal = nData4 + nCnt4;
        init_kernel<<<(initTotal + 255) / 256, 256, 0, stream>>>(
            (uint4*)d_out, (uint4*)d_ws, nData4, nCnt4);
        dim3 sgrid((N + 255) / 256, NB);
        scatter_kernel<<<sgrid, 256, 0, stream>>>(coords, attrs, bits, counts,
                                                  N, C);
        finalize_kernel<<<(initTotal + 255) / 256, 256, 0, stream>>>(
            bits, counts, occ, C);
    }
}